// Round 1
// baseline (5958.829 us; speedup 1.0000x reference)
//
#include <hip/hip_runtime.h>
#include <hip/hip_bf16.h>
#include <stdint.h>

#define N_NODES 25000
#define M_PAD   25088          // 196 * 128
#define E_EDGES 400000
#define NE      (E_EDGES + N_NODES)   // 425000 (edges + self loops)
#define HEADS   4
#define D_DIM   1024           // H*C = D_IN = 1024
#define NEG_SLOPE 0.2f

using bf16x8  = __attribute__((ext_vector_type(8))) short;
using floatx4 = __attribute__((ext_vector_type(4))) float;

__device__ __forceinline__ unsigned short f2bf(float f) {
    union { float f; unsigned u; } v{f};
    unsigned r = v.u + 0x7fffu + ((v.u >> 16) & 1u);   // round-to-nearest-even
    return (unsigned short)(r >> 16);
}
__device__ __forceinline__ float bf2f(unsigned short s) {
    union { unsigned u; float f; } v{(unsigned)s << 16};
    return v.f;
}

// ---------------- convert x (fp32 -> bf16, zero-pad rows to M_PAD) ----------
__global__ __launch_bounds__(256) void k_convert_x(
        const float* __restrict__ x, unsigned short* __restrict__ xb) {
    int i = blockIdx.x * 256 + threadIdx.x;          // quad index
    int row = i >> 8;                                // 256 quads per row
    if (row >= M_PAD) return;
    ushort4 o;
    if (row < N_NODES) {
        float4 v = ((const float4*)x)[i];
        o = make_ushort4(f2bf(v.x), f2bf(v.y), f2bf(v.z), f2bf(v.w));
    } else {
        o = make_ushort4(0, 0, 0, 0);
    }
    ((ushort4*)xb)[i] = o;
}

// ---------------- convert W (fp32 [K][N] -> bf16 transposed [N][K]) ---------
__global__ void k_convert_wt(const float* __restrict__ W,
                             unsigned short* __restrict__ Wt) {
    __shared__ float tile[32][33];
    int bx = blockIdx.x, by = blockIdx.y;
    int tx = threadIdx.x, ty = threadIdx.y;          // 32 x 8
    #pragma unroll
    for (int i = 0; i < 32; i += 8) {
        int k = by * 32 + ty + i;
        int n = bx * 32 + tx;
        tile[ty + i][tx] = W[(size_t)k * D_DIM + n];
    }
    __syncthreads();
    #pragma unroll
    for (int i = 0; i < 32; i += 8) {
        int n = bx * 32 + ty + i;
        int k = by * 32 + tx;
        Wt[(size_t)n * D_DIM + k] = f2bf(tile[tx][ty + i]);
    }
}

// ---------------- GEMM: xp = x @ W   (bf16 MFMA, 128x128 tile, BK=32) -------
// A: [M_PAD][1024] bf16 row-major; Bt: [1024 n][1024 k] bf16 (W transposed);
// C: [M_PAD][1024] bf16.
__global__ __launch_bounds__(256) void k_gemm(
        const unsigned short* __restrict__ A,
        const unsigned short* __restrict__ Bt,
        unsigned short* __restrict__ C) {
    __shared__ __align__(16) unsigned short As[128 * 32];
    __shared__ __align__(16) unsigned short Bs[128 * 32];

    const int tid  = threadIdx.x;
    const int m0   = blockIdx.x * 128;
    const int n0   = blockIdx.y * 128;
    const int wave = tid >> 6, lane = tid & 63;
    const int wm   = (wave & 1) * 64, wn = (wave >> 1) * 64;
    const int lrow = lane & 15;          // m (A) / n (B) / col (D) within 16
    const int quad = lane >> 4;          // 0..3

    floatx4 acc[4][4] = {};

    for (int k0 = 0; k0 < D_DIM; k0 += 32) {
        // stage A-tile (128x32) and B-tile (128n x 32k) into LDS
        #pragma unroll
        for (int s = 0; s < 2; ++s) {
            int q  = tid + s * 256;
            int r  = q >> 2;
            int c8 = (q & 3) * 8;
            *(int4*)(&As[r * 32 + c8]) =
                *(const int4*)(&A[(size_t)(m0 + r) * D_DIM + k0 + c8]);
            *(int4*)(&Bs[r * 32 + c8]) =
                *(const int4*)(&Bt[(size_t)(n0 + r) * D_DIM + k0 + c8]);
        }
        __syncthreads();

        bf16x8 af[4], bfr[4];
        #pragma unroll
        for (int mi = 0; mi < 4; ++mi)
            af[mi] = *(const bf16x8*)(&As[(wm + mi * 16 + lrow) * 32 + quad * 8]);
        #pragma unroll
        for (int ni = 0; ni < 4; ++ni)
            bfr[ni] = *(const bf16x8*)(&Bs[(wn + ni * 16 + lrow) * 32 + quad * 8]);

        #pragma unroll
        for (int mi = 0; mi < 4; ++mi)
            #pragma unroll
            for (int ni = 0; ni < 4; ++ni)
                acc[mi][ni] = __builtin_amdgcn_mfma_f32_16x16x32_bf16(
                    af[mi], bfr[ni], acc[mi][ni], 0, 0, 0);
        __syncthreads();
    }

    // epilogue: D row = quad*4 + r, col = lrow
    #pragma unroll
    for (int mi = 0; mi < 4; ++mi) {
        #pragma unroll
        for (int ni = 0; ni < 4; ++ni) {
            #pragma unroll
            for (int r = 0; r < 4; ++r) {
                int gm = m0 + wm + mi * 16 + quad * 4 + r;
                int gn = n0 + wn + ni * 16 + lrow;
                C[(size_t)gm * D_DIM + gn] = f2bf(acc[mi][ni][r]);
            }
        }
    }
}

// ---------------- per-node attention logits a_src/a_dst [N][H] --------------
__global__ __launch_bounds__(256) void k_node_logits(
        const unsigned short* __restrict__ xp,
        const float* __restrict__ att_src, const float* __restrict__ att_dst,
        float* __restrict__ a_src, float* __restrict__ a_dst) {
    int n = blockIdx.x;
    int tid = threadIdx.x;
    int h = tid >> 6, lane = tid & 63;
    int c = h * 256 + lane * 4;
    ushort4 v  = *(const ushort4*)(&xp[(size_t)n * D_DIM + c]);
    float4 as  = *(const float4*)(&att_src[c]);
    float4 ad  = *(const float4*)(&att_dst[c]);
    float x0 = bf2f(v.x), x1 = bf2f(v.y), x2 = bf2f(v.z), x3 = bf2f(v.w);
    float s = x0 * as.x + x1 * as.y + x2 * as.z + x3 * as.w;
    float d = x0 * ad.x + x1 * ad.y + x2 * ad.z + x3 * ad.w;
    #pragma unroll
    for (int off = 32; off > 0; off >>= 1) {
        s += __shfl_down(s, off);
        d += __shfl_down(d, off);
    }
    if (lane == 0) { a_src[n * 4 + h] = s; a_dst[n * 4 + h] = d; }
}

// ---------------- edge exp + denominator (no max-sub: |e| <~ 15, safe) ------
__global__ __launch_bounds__(256) void k_edge_exp(
        const int* __restrict__ ei,
        const float* __restrict__ a_src, const float* __restrict__ a_dst,
        float* __restrict__ ee, float* __restrict__ z) {
    int e = blockIdx.x * 256 + threadIdx.x;
    if (e >= NE) return;
    int s, d;
    if (e < E_EDGES) { s = ei[e]; d = ei[E_EDGES + e]; }
    else             { s = d = e - E_EDGES; }
    float4 as = *(const float4*)(&a_src[s * 4]);
    float4 ad = *(const float4*)(&a_dst[d * 4]);
    float l0 = as.x + ad.x, l1 = as.y + ad.y, l2 = as.z + ad.z, l3 = as.w + ad.w;
    l0 = l0 > 0.f ? l0 : NEG_SLOPE * l0;
    l1 = l1 > 0.f ? l1 : NEG_SLOPE * l1;
    l2 = l2 > 0.f ? l2 : NEG_SLOPE * l2;
    l3 = l3 > 0.f ? l3 : NEG_SLOPE * l3;
    float e0 = __expf(l0), e1 = __expf(l1), e2 = __expf(l2), e3 = __expf(l3);
    *(float4*)(&ee[e * 4]) = make_float4(e0, e1, e2, e3);
    atomicAdd(&z[d * 4 + 0], e0);
    atomicAdd(&z[d * 4 + 1], e1);
    atomicAdd(&z[d * 4 + 2], e2);
    atomicAdd(&z[d * 4 + 3], e3);
}

// ---------------- aggregation: out[dst] += alpha * xp[src] ------------------
// one wave (64 lanes) per edge; lane l: channels {h*256 + l*4 .. +3} per head
__global__ __launch_bounds__(256) void k_aggregate(
        const int* __restrict__ ei,
        const unsigned short* __restrict__ xp,
        const float* __restrict__ ee, const float* __restrict__ z,
        float* __restrict__ out) {
    int t = blockIdx.x * 256 + threadIdx.x;
    int e = t >> 6;
    int lane = t & 63;
    if (e >= NE) return;
    int s, d;
    if (e < E_EDGES) { s = ei[e]; d = ei[E_EDGES + e]; }
    else             { s = d = e - E_EDGES; }
    float4 eev = *(const float4*)(&ee[e * 4]);
    float4 zv  = *(const float4*)(&z[d * 4]);
    float al[4] = { eev.x / zv.x, eev.y / zv.y, eev.z / zv.z, eev.w / zv.w };
    size_t sb = (size_t)s * D_DIM, db = (size_t)d * D_DIM;
    #pragma unroll
    for (int h = 0; h < 4; ++h) {
        int c = h * 256 + lane * 4;
        ushort4 v = *(const ushort4*)(&xp[sb + c]);
        float a = al[h];
        atomicAdd(&out[db + c + 0], a * bf2f(v.x));
        atomicAdd(&out[db + c + 1], a * bf2f(v.y));
        atomicAdd(&out[db + c + 2], a * bf2f(v.z));
        atomicAdd(&out[db + c + 3], a * bf2f(v.w));
    }
}

// ---------------- bias + relu ----------------------------------------------
__global__ __launch_bounds__(256) void k_bias_relu(
        float* __restrict__ out, const float* __restrict__ bias) {
    int i = blockIdx.x * 256 + threadIdx.x;          // quad index
    if (i >= N_NODES * 256) return;
    float4 v = ((float4*)out)[i];
    float4 b = ((const float4*)bias)[i & 255];
    v.x = fmaxf(v.x + b.x, 0.f);
    v.y = fmaxf(v.y + b.y, 0.f);
    v.z = fmaxf(v.z + b.z, 0.f);
    v.w = fmaxf(v.w + b.w, 0.f);
    ((float4*)out)[i] = v;
}

extern "C" void kernel_launch(void* const* d_in, const int* in_sizes, int n_in,
                              void* d_out, int out_size, void* d_ws, size_t ws_size,
                              hipStream_t stream) {
    const float* x       = (const float*)d_in[0];
    const int*   ei      = (const int*)d_in[1];      // [2][E] int32
    const float* W       = (const float*)d_in[2];
    const float* att_src = (const float*)d_in[3];
    const float* att_dst = (const float*)d_in[4];
    const float* bias    = (const float*)d_in[5];
    float* out = (float*)d_out;

    char* ws = (char*)d_ws;
    size_t off = 0;
    auto alloc = [&](size_t bytes) -> void* {
        void* p = ws + off;
        off = (off + bytes + 255) & ~(size_t)255;
        return p;
    };
    unsigned short* xb  = (unsigned short*)alloc((size_t)M_PAD * D_DIM * 2);
    unsigned short* Wt  = (unsigned short*)alloc((size_t)D_DIM * D_DIM * 2);
    unsigned short* xpb = (unsigned short*)alloc((size_t)M_PAD * D_DIM * 2);
    float* a_src = (float*)alloc((size_t)N_NODES * 4 * 4);
    float* a_dst = (float*)alloc((size_t)N_NODES * 4 * 4);
    float* z     = (float*)alloc((size_t)N_NODES * 4 * 4);
    float* ee    = (float*)alloc((size_t)NE * 4 * 4);

    hipMemsetAsync(z, 0, (size_t)N_NODES * 4 * 4, stream);
    hipMemsetAsync(d_out, 0, (size_t)out_size * 4, stream);

    k_convert_x<<<M_PAD, 256, 0, stream>>>(x, xb);
    k_convert_wt<<<dim3(32, 32), dim3(32, 8), 0, stream>>>(W, Wt);
    k_gemm<<<dim3(M_PAD / 128, D_DIM / 128), 256, 0, stream>>>(xb, Wt, xpb);
    k_node_logits<<<N_NODES, 256, 0, stream>>>(xpb, att_src, att_dst, a_src, a_dst);
    k_edge_exp<<<(NE + 255) / 256, 256, 0, stream>>>(ei, a_src, a_dst, ee, z);
    k_aggregate<<<((size_t)NE * 64 + 255) / 256, 256, 0, stream>>>(ei, xpb, ee, z, out);
    k_bias_relu<<<(N_NODES * 256 + 255) / 256, 256, 0, stream>>>(out, bias);
}

// Round 2
// 467.914 us; speedup vs baseline: 12.7349x; 12.7349x over previous
//
#include <hip/hip_runtime.h>
#include <hip/hip_bf16.h>
#include <stdint.h>

#define N_NODES 25000
#define M_PAD   25088          // 196 * 128
#define E_EDGES 400000
#define NE      (E_EDGES + N_NODES)   // 425000 (edges + self loops)
#define HEADS   4
#define D_DIM   1024           // H*C = D_IN = 1024
#define NEG_SLOPE 0.2f
#define NBLK_SCAN ((N_NODES + 255) / 256)   // 98

using bf16x8  = __attribute__((ext_vector_type(8))) short;
using floatx4 = __attribute__((ext_vector_type(4))) float;

__device__ __forceinline__ unsigned short f2bf(float f) {
    union { float f; unsigned u; } v{f};
    unsigned r = v.u + 0x7fffu + ((v.u >> 16) & 1u);   // round-to-nearest-even
    return (unsigned short)(r >> 16);
}
__device__ __forceinline__ float bf2f(unsigned short s) {
    union { unsigned u; float f; } v{(unsigned)s << 16};
    return v.f;
}

// ---------------- convert x (fp32 -> bf16, zero-pad rows to M_PAD) ----------
__global__ __launch_bounds__(256) void k_convert_x(
        const float* __restrict__ x, unsigned short* __restrict__ xb) {
    int i = blockIdx.x * 256 + threadIdx.x;          // quad index
    int row = i >> 8;                                // 256 quads per row
    if (row >= M_PAD) return;
    ushort4 o;
    if (row < N_NODES) {
        float4 v = ((const float4*)x)[i];
        o = make_ushort4(f2bf(v.x), f2bf(v.y), f2bf(v.z), f2bf(v.w));
    } else {
        o = make_ushort4(0, 0, 0, 0);
    }
    ((ushort4*)xb)[i] = o;
}

// ---------------- convert W (fp32 [K][N] -> bf16 transposed [N][K]) ---------
__global__ void k_convert_wt(const float* __restrict__ W,
                             unsigned short* __restrict__ Wt) {
    __shared__ float tile[32][33];
    int bx = blockIdx.x, by = blockIdx.y;
    int tx = threadIdx.x, ty = threadIdx.y;          // 32 x 8
    #pragma unroll
    for (int i = 0; i < 32; i += 8) {
        int k = by * 32 + ty + i;
        int n = bx * 32 + tx;
        tile[ty + i][tx] = W[(size_t)k * D_DIM + n];
    }
    __syncthreads();
    #pragma unroll
    for (int i = 0; i < 32; i += 8) {
        int n = bx * 32 + ty + i;
        int k = by * 32 + tx;
        Wt[(size_t)n * D_DIM + k] = f2bf(tile[tx][ty + i]);
    }
}

// ---------------- GEMM: xp = x @ W   (bf16 MFMA, 128x128 tile, BK=32) -------
__global__ __launch_bounds__(256) void k_gemm(
        const unsigned short* __restrict__ A,
        const unsigned short* __restrict__ Bt,
        unsigned short* __restrict__ C) {
    __shared__ __align__(16) unsigned short As[128 * 32];
    __shared__ __align__(16) unsigned short Bs[128 * 32];

    const int tid  = threadIdx.x;
    const int m0   = blockIdx.x * 128;
    const int n0   = blockIdx.y * 128;
    const int wave = tid >> 6, lane = tid & 63;
    const int wm   = (wave & 1) * 64, wn = (wave >> 1) * 64;
    const int lrow = lane & 15;
    const int quad = lane >> 4;

    floatx4 acc[4][4] = {};

    for (int k0 = 0; k0 < D_DIM; k0 += 32) {
        #pragma unroll
        for (int s = 0; s < 2; ++s) {
            int q  = tid + s * 256;
            int r  = q >> 2;
            int c8 = (q & 3) * 8;
            *(int4*)(&As[r * 32 + c8]) =
                *(const int4*)(&A[(size_t)(m0 + r) * D_DIM + k0 + c8]);
            *(int4*)(&Bs[r * 32 + c8]) =
                *(const int4*)(&Bt[(size_t)(n0 + r) * D_DIM + k0 + c8]);
        }
        __syncthreads();

        bf16x8 af[4], bfr[4];
        #pragma unroll
        for (int mi = 0; mi < 4; ++mi)
            af[mi] = *(const bf16x8*)(&As[(wm + mi * 16 + lrow) * 32 + quad * 8]);
        #pragma unroll
        for (int ni = 0; ni < 4; ++ni)
            bfr[ni] = *(const bf16x8*)(&Bs[(wn + ni * 16 + lrow) * 32 + quad * 8]);

        #pragma unroll
        for (int mi = 0; mi < 4; ++mi)
            #pragma unroll
            for (int ni = 0; ni < 4; ++ni)
                acc[mi][ni] = __builtin_amdgcn_mfma_f32_16x16x32_bf16(
                    af[mi], bfr[ni], acc[mi][ni], 0, 0, 0);
        __syncthreads();
    }

    #pragma unroll
    for (int mi = 0; mi < 4; ++mi) {
        #pragma unroll
        for (int ni = 0; ni < 4; ++ni) {
            #pragma unroll
            for (int r = 0; r < 4; ++r) {
                int gm = m0 + wm + mi * 16 + quad * 4 + r;
                int gn = n0 + wn + ni * 16 + lrow;
                C[(size_t)gm * D_DIM + gn] = f2bf(acc[mi][ni][r]);
            }
        }
    }
}

// ---------------- per-node attention logits a_src/a_dst [N][H] --------------
__global__ __launch_bounds__(256) void k_node_logits(
        const unsigned short* __restrict__ xp,
        const float* __restrict__ att_src, const float* __restrict__ att_dst,
        float* __restrict__ a_src, float* __restrict__ a_dst) {
    int n = blockIdx.x;
    int tid = threadIdx.x;
    int h = tid >> 6, lane = tid & 63;
    int c = h * 256 + lane * 4;
    ushort4 v  = *(const ushort4*)(&xp[(size_t)n * D_DIM + c]);
    float4 as  = *(const float4*)(&att_src[c]);
    float4 ad  = *(const float4*)(&att_dst[c]);
    float x0 = bf2f(v.x), x1 = bf2f(v.y), x2 = bf2f(v.z), x3 = bf2f(v.w);
    float s = x0 * as.x + x1 * as.y + x2 * as.z + x3 * as.w;
    float d = x0 * ad.x + x1 * ad.y + x2 * ad.z + x3 * ad.w;
    #pragma unroll
    for (int off = 32; off > 0; off >>= 1) {
        s += __shfl_down(s, off);
        d += __shfl_down(d, off);
    }
    if (lane == 0) { a_src[n * 4 + h] = s; a_dst[n * 4 + h] = d; }
}

// ---------------- degree count (incl. self loops) ---------------------------
__global__ __launch_bounds__(256) void k_deg(
        const int* __restrict__ ei, int* __restrict__ deg) {
    int e = blockIdx.x * 256 + threadIdx.x;
    if (e >= NE) return;
    int d = (e < E_EDGES) ? ei[E_EDGES + e] : (e - E_EDGES);
    atomicAdd(&deg[d], 1);
}

// ---------------- 3-phase exclusive scan of deg -> rowstart -----------------
__global__ __launch_bounds__(256) void k_scan1(
        const int* __restrict__ deg, int* __restrict__ rowstart,
        int* __restrict__ blocksum) {
    __shared__ int smem[256];
    int i = blockIdx.x * 256 + threadIdx.x;
    int v = (i < N_NODES) ? deg[i] : 0;
    smem[threadIdx.x] = v;
    __syncthreads();
    #pragma unroll
    for (int off = 1; off < 256; off <<= 1) {
        int t = (threadIdx.x >= off) ? smem[threadIdx.x - off] : 0;
        __syncthreads();
        smem[threadIdx.x] += t;
        __syncthreads();
    }
    if (i < N_NODES) rowstart[i] = smem[threadIdx.x] - v;   // local exclusive
    if (threadIdx.x == 255) blocksum[blockIdx.x] = smem[255];
}

__global__ __launch_bounds__(128) void k_scan2(
        const int* __restrict__ blocksum, int* __restrict__ blockoff) {
    __shared__ int smem[128];
    int v = (threadIdx.x < NBLK_SCAN) ? blocksum[threadIdx.x] : 0;
    smem[threadIdx.x] = v;
    __syncthreads();
    #pragma unroll
    for (int off = 1; off < 128; off <<= 1) {
        int t = (threadIdx.x >= off) ? smem[threadIdx.x - off] : 0;
        __syncthreads();
        smem[threadIdx.x] += t;
        __syncthreads();
    }
    blockoff[threadIdx.x] = smem[threadIdx.x] - v;          // exclusive
}

__global__ __launch_bounds__(256) void k_scan3(
        int* __restrict__ rowstart, const int* __restrict__ blockoff) {
    int i = blockIdx.x * 256 + threadIdx.x;
    if (i < N_NODES) rowstart[i] += blockoff[blockIdx.x];
    if (i == 0) rowstart[N_NODES] = NE;
}

// ---------------- edge exp + scatter into CSR slots -------------------------
// (no max-subtraction: |logit| small, exp() cannot overflow fp32; alpha is
//  shift-invariant so result matches the reference)
__global__ __launch_bounds__(256) void k_edge_exp_scatter(
        const int* __restrict__ ei,
        const float* __restrict__ a_src, const float* __restrict__ a_dst,
        const int* __restrict__ rowstart, int* __restrict__ cursor,
        int* __restrict__ csr_src, float* __restrict__ csr_ee) {
    int e = blockIdx.x * 256 + threadIdx.x;
    if (e >= NE) return;
    int s, d;
    if (e < E_EDGES) { s = ei[e]; d = ei[E_EDGES + e]; }
    else             { s = d = e - E_EDGES; }
    float4 as = *(const float4*)(&a_src[s * 4]);
    float4 ad = *(const float4*)(&a_dst[d * 4]);
    float l0 = as.x + ad.x, l1 = as.y + ad.y, l2 = as.z + ad.z, l3 = as.w + ad.w;
    l0 = l0 > 0.f ? l0 : NEG_SLOPE * l0;
    l1 = l1 > 0.f ? l1 : NEG_SLOPE * l1;
    l2 = l2 > 0.f ? l2 : NEG_SLOPE * l2;
    l3 = l3 > 0.f ? l3 : NEG_SLOPE * l3;
    int pos  = atomicAdd(&cursor[d], 1);
    int slot = rowstart[d] + pos;
    csr_src[slot] = s;
    *(float4*)(&csr_ee[(size_t)slot * 4]) =
        make_float4(__expf(l0), __expf(l1), __expf(l2), __expf(l3));
}

// ---------------- per-node aggregation (no atomics) -------------------------
// one block (256 threads) per dst node; thread t covers channels 4t..4t+3,
// all within head h = t>>6. Register accumulate, fused bias+relu store.
__global__ __launch_bounds__(256) void k_node_aggregate(
        const int* __restrict__ csr_src, const float* __restrict__ csr_ee,
        const int* __restrict__ rowstart,
        const unsigned short* __restrict__ xp,
        const float* __restrict__ bias, float* __restrict__ out) {
    int n   = blockIdx.x;
    int tid = threadIdx.x;
    int row = rowstart[n];
    int deg = rowstart[n + 1] - row;

    __shared__ float zsh[4];
    if (tid < 64) {
        float z0 = 0.f, z1 = 0.f, z2 = 0.f, z3 = 0.f;
        for (int i = tid; i < deg; i += 64) {
            float4 v = *(const float4*)(&csr_ee[(size_t)(row + i) * 4]);
            z0 += v.x; z1 += v.y; z2 += v.z; z3 += v.w;
        }
        #pragma unroll
        for (int off = 32; off > 0; off >>= 1) {
            z0 += __shfl_down(z0, off);
            z1 += __shfl_down(z1, off);
            z2 += __shfl_down(z2, off);
            z3 += __shfl_down(z3, off);
        }
        if (tid == 0) { zsh[0] = z0; zsh[1] = z1; zsh[2] = z2; zsh[3] = z3; }
    }
    __syncthreads();

    int h = tid >> 6;
    int c = tid * 4;
    float rz = 1.0f / zsh[h];
    float a0 = 0.f, a1 = 0.f, a2 = 0.f, a3 = 0.f;
    for (int i = 0; i < deg; ++i) {
        int s   = csr_src[row + i];                        // uniform per block
        float a = csr_ee[(size_t)(row + i) * 4 + h] * rz;  // uniform per wave
        ushort4 v = *(const ushort4*)(&xp[(size_t)s * D_DIM + c]);
        a0 += a * bf2f(v.x);
        a1 += a * bf2f(v.y);
        a2 += a * bf2f(v.z);
        a3 += a * bf2f(v.w);
    }
    float4 b = *(const float4*)(&bias[c]);
    float4 o;
    o.x = fmaxf(a0 + b.x, 0.f);
    o.y = fmaxf(a1 + b.y, 0.f);
    o.z = fmaxf(a2 + b.z, 0.f);
    o.w = fmaxf(a3 + b.w, 0.f);
    *(float4*)(&out[(size_t)n * D_DIM + c]) = o;
}

extern "C" void kernel_launch(void* const* d_in, const int* in_sizes, int n_in,
                              void* d_out, int out_size, void* d_ws, size_t ws_size,
                              hipStream_t stream) {
    const float* x       = (const float*)d_in[0];
    const int*   ei      = (const int*)d_in[1];      // [2][E] int32
    const float* W       = (const float*)d_in[2];
    const float* att_src = (const float*)d_in[3];
    const float* att_dst = (const float*)d_in[4];
    const float* bias    = (const float*)d_in[5];
    float* out = (float*)d_out;

    char* ws = (char*)d_ws;
    size_t off = 0;
    auto alloc = [&](size_t bytes) -> void* {
        void* p = ws + off;
        off = (off + bytes + 255) & ~(size_t)255;
        return p;
    };
    unsigned short* xb   = (unsigned short*)alloc((size_t)M_PAD * D_DIM * 2);
    unsigned short* Wt   = (unsigned short*)alloc((size_t)D_DIM * D_DIM * 2);
    unsigned short* xpb  = (unsigned short*)alloc((size_t)M_PAD * D_DIM * 2);
    float* a_src    = (float*)alloc((size_t)N_NODES * 4 * 4);
    float* a_dst    = (float*)alloc((size_t)N_NODES * 4 * 4);
    int*   deg      = (int*)alloc((size_t)N_NODES * 4);
    int*   rowstart = (int*)alloc((size_t)(N_NODES + 1) * 4);
    int*   cursor   = (int*)alloc((size_t)N_NODES * 4);
    int*   blocksum = (int*)alloc((size_t)NBLK_SCAN * 4);
    int*   blockoff = (int*)alloc((size_t)128 * 4);
    int*   csr_src  = (int*)alloc((size_t)NE * 4);
    float* csr_ee   = (float*)alloc((size_t)NE * 4 * 4);

    hipMemsetAsync(deg, 0, (size_t)N_NODES * 4, stream);
    hipMemsetAsync(cursor, 0, (size_t)N_NODES * 4, stream);

    k_convert_x<<<M_PAD, 256, 0, stream>>>(x, xb);
    k_convert_wt<<<dim3(32, 32), dim3(32, 8), 0, stream>>>(W, Wt);
    k_gemm<<<dim3(M_PAD / 128, D_DIM / 128), 256, 0, stream>>>(xb, Wt, xpb);
    k_node_logits<<<N_NODES, 256, 0, stream>>>(xpb, att_src, att_dst, a_src, a_dst);
    k_deg<<<(NE + 255) / 256, 256, 0, stream>>>(ei, deg);
    k_scan1<<<NBLK_SCAN, 256, 0, stream>>>(deg, rowstart, blocksum);
    k_scan2<<<1, 128, 0, stream>>>(blocksum, blockoff);
    k_scan3<<<NBLK_SCAN, 256, 0, stream>>>(rowstart, blockoff);
    k_edge_exp_scatter<<<(NE + 255) / 256, 256, 0, stream>>>(
        ei, a_src, a_dst, rowstart, cursor, csr_src, csr_ee);
    k_node_aggregate<<<N_NODES, 256, 0, stream>>>(
        csr_src, csr_ee, rowstart, xpb, bias, out);
}

// Round 3
// 464.996 us; speedup vs baseline: 12.8148x; 1.0063x over previous
//
#include <hip/hip_runtime.h>
#include <hip/hip_bf16.h>
#include <stdint.h>

#define N_NODES 25000
#define M_PAD   25088          // 196 * 128
#define E_EDGES 400000
#define NE      (E_EDGES + N_NODES)   // 425000 (edges + self loops)
#define HEADS   4
#define D_DIM   1024           // H*C = D_IN = 1024
#define NEG_SLOPE 0.2f
#define NBLK_SCAN ((N_NODES + 255) / 256)   // 98

using bf16x8  = __attribute__((ext_vector_type(8))) short;
using floatx4 = __attribute__((ext_vector_type(4))) float;
using ushort8 = __attribute__((ext_vector_type(8))) unsigned short;

__device__ __forceinline__ unsigned short f2bf(float f) {
    union { float f; unsigned u; } v{f};
    unsigned r = v.u + 0x7fffu + ((v.u >> 16) & 1u);   // round-to-nearest-even
    return (unsigned short)(r >> 16);
}
__device__ __forceinline__ float bf2f(unsigned short s) {
    union { unsigned u; float f; } v{(unsigned)s << 16};
    return v.f;
}

// ---------------- convert x (fp32 -> bf16, zero-pad rows to M_PAD) ----------
__global__ __launch_bounds__(256) void k_convert_x(
        const float* __restrict__ x, unsigned short* __restrict__ xb) {
    int i = blockIdx.x * 256 + threadIdx.x;          // quad index
    int row = i >> 8;                                // 256 quads per row
    if (row >= M_PAD) return;
    ushort4 o;
    if (row < N_NODES) {
        float4 v = ((const float4*)x)[i];
        o = make_ushort4(f2bf(v.x), f2bf(v.y), f2bf(v.z), f2bf(v.w));
    } else {
        o = make_ushort4(0, 0, 0, 0);
    }
    ((ushort4*)xb)[i] = o;
}

// ---------------- convert W (fp32 [K][N] -> bf16 transposed [N][K]) ---------
__global__ void k_convert_wt(const float* __restrict__ W,
                             unsigned short* __restrict__ Wt) {
    __shared__ float tile[32][33];
    int bx = blockIdx.x, by = blockIdx.y;
    int tx = threadIdx.x, ty = threadIdx.y;          // 32 x 8
    #pragma unroll
    for (int i = 0; i < 32; i += 8) {
        int k = by * 32 + ty + i;
        int n = bx * 32 + tx;
        tile[ty + i][tx] = W[(size_t)k * D_DIM + n];
    }
    __syncthreads();
    #pragma unroll
    for (int i = 0; i < 32; i += 8) {
        int n = bx * 32 + ty + i;
        int k = by * 32 + tx;
        Wt[(size_t)n * D_DIM + k] = f2bf(tile[tx][ty + i]);
    }
}

// ---------------- GEMM: xp = x @ W   (bf16 MFMA, 128x128 tile, BK=32) -------
// Staging via global_load_lds width=16 (m97 pattern): LDS dst is wave-uniform
// base + lane*16, so the LDS layout must be contiguous in lane order.
// A-tile rows are 32 bf16 = 64 B; lane l covers row base+(l>>2), col (l&3)*8.
__global__ __launch_bounds__(256) void k_gemm(
        const unsigned short* __restrict__ A,
        const unsigned short* __restrict__ Bt,
        unsigned short* __restrict__ C) {
    __shared__ __align__(16) unsigned short As[128 * 32];
    __shared__ __align__(16) unsigned short Bs[128 * 32];

    const int tid  = threadIdx.x;
    const int m0   = blockIdx.x * 128;
    const int n0   = blockIdx.y * 128;
    const int wave = tid >> 6, lane = tid & 63;
    const int wm   = (wave & 1) * 64, wn = (wave >> 1) * 64;
    const int lrow = lane & 15;
    const int quad = lane >> 4;

    const int srow = (lane >> 2);        // 0..15 row within 16-row chunk
    const int scol = (lane & 3) * 8;     // 0,8,16,24

    floatx4 acc[4][4] = {};

    for (int k0 = 0; k0 < D_DIM; k0 += 32) {
        // stage A-tile and B-tile via async global->LDS, 16 B per lane
        #pragma unroll
        for (int j = 0; j < 2; ++j) {
            int rbase = wave * 32 + j * 16;
            const unsigned short* ga =
                &A[(size_t)(m0 + rbase + srow) * D_DIM + k0 + scol];
            const unsigned short* gb =
                &Bt[(size_t)(n0 + rbase + srow) * D_DIM + k0 + scol];
            __builtin_amdgcn_global_load_lds(
                (const __attribute__((address_space(1))) void*)ga,
                (__attribute__((address_space(3))) void*)&As[rbase * 32],
                16, 0, 0);
            __builtin_amdgcn_global_load_lds(
                (const __attribute__((address_space(1))) void*)gb,
                (__attribute__((address_space(3))) void*)&Bs[rbase * 32],
                16, 0, 0);
        }
        __syncthreads();

        bf16x8 af[4], bfr[4];
        #pragma unroll
        for (int mi = 0; mi < 4; ++mi)
            af[mi] = *(const bf16x8*)(&As[(wm + mi * 16 + lrow) * 32 + quad * 8]);
        #pragma unroll
        for (int ni = 0; ni < 4; ++ni)
            bfr[ni] = *(const bf16x8*)(&Bs[(wn + ni * 16 + lrow) * 32 + quad * 8]);

        #pragma unroll
        for (int mi = 0; mi < 4; ++mi)
            #pragma unroll
            for (int ni = 0; ni < 4; ++ni)
                acc[mi][ni] = __builtin_amdgcn_mfma_f32_16x16x32_bf16(
                    af[mi], bfr[ni], acc[mi][ni], 0, 0, 0);
        __syncthreads();
    }

    #pragma unroll
    for (int mi = 0; mi < 4; ++mi) {
        #pragma unroll
        for (int ni = 0; ni < 4; ++ni) {
            #pragma unroll
            for (int r = 0; r < 4; ++r) {
                int gm = m0 + wm + mi * 16 + quad * 4 + r;
                int gn = n0 + wn + ni * 16 + lrow;
                C[(size_t)gm * D_DIM + gn] = f2bf(acc[mi][ni][r]);
            }
        }
    }
}

// ---------------- per-node attention logits a_src/a_dst [N][H] --------------
__global__ __launch_bounds__(256) void k_node_logits(
        const unsigned short* __restrict__ xp,
        const float* __restrict__ att_src, const float* __restrict__ att_dst,
        float* __restrict__ a_src, float* __restrict__ a_dst) {
    int n = blockIdx.x;
    int tid = threadIdx.x;
    int h = tid >> 6, lane = tid & 63;
    int c = h * 256 + lane * 4;
    ushort4 v  = *(const ushort4*)(&xp[(size_t)n * D_DIM + c]);
    float4 as  = *(const float4*)(&att_src[c]);
    float4 ad  = *(const float4*)(&att_dst[c]);
    float x0 = bf2f(v.x), x1 = bf2f(v.y), x2 = bf2f(v.z), x3 = bf2f(v.w);
    float s = x0 * as.x + x1 * as.y + x2 * as.z + x3 * as.w;
    float d = x0 * ad.x + x1 * ad.y + x2 * ad.z + x3 * ad.w;
    #pragma unroll
    for (int off = 32; off > 0; off >>= 1) {
        s += __shfl_down(s, off);
        d += __shfl_down(d, off);
    }
    if (lane == 0) { a_src[n * 4 + h] = s; a_dst[n * 4 + h] = d; }
}

// ---------------- degree count (incl. self loops) ---------------------------
__global__ __launch_bounds__(256) void k_deg(
        const int* __restrict__ ei, int* __restrict__ deg) {
    int e = blockIdx.x * 256 + threadIdx.x;
    if (e >= NE) return;
    int d = (e < E_EDGES) ? ei[E_EDGES + e] : (e - E_EDGES);
    atomicAdd(&deg[d], 1);
}

// ---------------- 3-phase exclusive scan of deg -> rowstart -----------------
__global__ __launch_bounds__(256) void k_scan1(
        const int* __restrict__ deg, int* __restrict__ rowstart,
        int* __restrict__ blocksum) {
    __shared__ int smem[256];
    int i = blockIdx.x * 256 + threadIdx.x;
    int v = (i < N_NODES) ? deg[i] : 0;
    smem[threadIdx.x] = v;
    __syncthreads();
    #pragma unroll
    for (int off = 1; off < 256; off <<= 1) {
        int t = (threadIdx.x >= off) ? smem[threadIdx.x - off] : 0;
        __syncthreads();
        smem[threadIdx.x] += t;
        __syncthreads();
    }
    if (i < N_NODES) rowstart[i] = smem[threadIdx.x] - v;   // local exclusive
    if (threadIdx.x == 255) blocksum[blockIdx.x] = smem[255];
}

__global__ __launch_bounds__(128) void k_scan2(
        const int* __restrict__ blocksum, int* __restrict__ blockoff) {
    __shared__ int smem[128];
    int v = (threadIdx.x < NBLK_SCAN) ? blocksum[threadIdx.x] : 0;
    smem[threadIdx.x] = v;
    __syncthreads();
    #pragma unroll
    for (int off = 1; off < 128; off <<= 1) {
        int t = (threadIdx.x >= off) ? smem[threadIdx.x - off] : 0;
        __syncthreads();
        smem[threadIdx.x] += t;
        __syncthreads();
    }
    blockoff[threadIdx.x] = smem[threadIdx.x] - v;          // exclusive
}

__global__ __launch_bounds__(256) void k_scan3(
        int* __restrict__ rowstart, const int* __restrict__ blockoff) {
    int i = blockIdx.x * 256 + threadIdx.x;
    if (i < N_NODES) rowstart[i] += blockoff[blockIdx.x];
    if (i == 0) rowstart[N_NODES] = NE;
}

// ---------------- edge exp + scatter into CSR slots -------------------------
// (no max-subtraction: |logit| small, exp() cannot overflow fp32; alpha is
//  shift-invariant so result matches the reference)
__global__ __launch_bounds__(256) void k_edge_exp_scatter(
        const int* __restrict__ ei,
        const float* __restrict__ a_src, const float* __restrict__ a_dst,
        const int* __restrict__ rowstart, int* __restrict__ cursor,
        int* __restrict__ csr_src, float* __restrict__ csr_ee) {
    int e = blockIdx.x * 256 + threadIdx.x;
    if (e >= NE) return;
    int s, d;
    if (e < E_EDGES) { s = ei[e]; d = ei[E_EDGES + e]; }
    else             { s = d = e - E_EDGES; }
    float4 as = *(const float4*)(&a_src[s * 4]);
    float4 ad = *(const float4*)(&a_dst[d * 4]);
    float l0 = as.x + ad.x, l1 = as.y + ad.y, l2 = as.z + ad.z, l3 = as.w + ad.w;
    l0 = l0 > 0.f ? l0 : NEG_SLOPE * l0;
    l1 = l1 > 0.f ? l1 : NEG_SLOPE * l1;
    l2 = l2 > 0.f ? l2 : NEG_SLOPE * l2;
    l3 = l3 > 0.f ? l3 : NEG_SLOPE * l3;
    int pos  = atomicAdd(&cursor[d], 1);
    int slot = rowstart[d] + pos;
    csr_src[slot] = s;
    *(float4*)(&csr_ee[(size_t)slot * 4]) =
        make_float4(__expf(l0), __expf(l1), __expf(l2), __expf(l3));
}

// ---------------- per-node aggregation (no atomics) -------------------------
// 2 nodes per block: 128 threads per node, thread covers 8 channels (16 B
// gathers). Edge loop unrolled x4 with independent gathers to hide latency.
__device__ __forceinline__ void acc8(float* acc, float a, ushort8 v) {
    #pragma unroll
    for (int j = 0; j < 8; ++j) acc[j] += a * bf2f((unsigned short)v[j]);
}

__global__ __launch_bounds__(256) void k_node_aggregate(
        const int* __restrict__ csr_src, const float* __restrict__ csr_ee,
        const int* __restrict__ rowstart,
        const unsigned short* __restrict__ xp,
        const float* __restrict__ bias, float* __restrict__ out) {
    const int tid  = threadIdx.x;
    const int half = tid >> 7;                 // node within block
    const int n    = blockIdx.x * 2 + half;    // 12500*2 = 25000 exact
    const int t    = tid & 127;
    const int row  = rowstart[n];
    const int deg  = rowstart[n + 1] - row;

    __shared__ float zsh[2][4];
    if ((tid & 64) == 0) {                     // waves 0 (node0) and 2 (node1)
        int lane = tid & 63;
        float z0 = 0.f, z1 = 0.f, z2 = 0.f, z3 = 0.f;
        for (int i = lane; i < deg; i += 64) {
            float4 v = *(const float4*)(&csr_ee[(size_t)(row + i) * 4]);
            z0 += v.x; z1 += v.y; z2 += v.z; z3 += v.w;
        }
        #pragma unroll
        for (int off = 32; off > 0; off >>= 1) {
            z0 += __shfl_down(z0, off);
            z1 += __shfl_down(z1, off);
            z2 += __shfl_down(z2, off);
            z3 += __shfl_down(z3, off);
        }
        if (lane == 0) {
            zsh[half][0] = z0; zsh[half][1] = z1;
            zsh[half][2] = z2; zsh[half][3] = z3;
        }
    }
    __syncthreads();

    const int h = t >> 5;                      // head = (t*8)/256
    const int c = t * 8;                       // 8 channels, 16-B aligned
    const float rz = 1.0f / zsh[half][h];

    float acc[8] = {};
    int i = 0;
    for (; i + 4 <= deg; i += 4) {
        int s0 = csr_src[row + i + 0];
        int s1 = csr_src[row + i + 1];
        int s2 = csr_src[row + i + 2];
        int s3 = csr_src[row + i + 3];
        float a0 = csr_ee[(size_t)(row + i + 0) * 4 + h] * rz;
        float a1 = csr_ee[(size_t)(row + i + 1) * 4 + h] * rz;
        float a2 = csr_ee[(size_t)(row + i + 2) * 4 + h] * rz;
        float a3 = csr_ee[(size_t)(row + i + 3) * 4 + h] * rz;
        ushort8 v0 = *(const ushort8*)(&xp[(size_t)s0 * D_DIM + c]);
        ushort8 v1 = *(const ushort8*)(&xp[(size_t)s1 * D_DIM + c]);
        ushort8 v2 = *(const ushort8*)(&xp[(size_t)s2 * D_DIM + c]);
        ushort8 v3 = *(const ushort8*)(&xp[(size_t)s3 * D_DIM + c]);
        acc8(acc, a0, v0);
        acc8(acc, a1, v1);
        acc8(acc, a2, v2);
        acc8(acc, a3, v3);
    }
    for (; i < deg; ++i) {
        int s   = csr_src[row + i];
        float a = csr_ee[(size_t)(row + i) * 4 + h] * rz;
        ushort8 v = *(const ushort8*)(&xp[(size_t)s * D_DIM + c]);
        acc8(acc, a, v);
    }

    float4 b0 = *(const float4*)(&bias[c]);
    float4 b1 = *(const float4*)(&bias[c + 4]);
    float4 o0, o1;
    o0.x = fmaxf(acc[0] + b0.x, 0.f);
    o0.y = fmaxf(acc[1] + b0.y, 0.f);
    o0.z = fmaxf(acc[2] + b0.z, 0.f);
    o0.w = fmaxf(acc[3] + b0.w, 0.f);
    o1.x = fmaxf(acc[4] + b1.x, 0.f);
    o1.y = fmaxf(acc[5] + b1.y, 0.f);
    o1.z = fmaxf(acc[6] + b1.z, 0.f);
    o1.w = fmaxf(acc[7] + b1.w, 0.f);
    *(float4*)(&out[(size_t)n * D_DIM + c])     = o0;
    *(float4*)(&out[(size_t)n * D_DIM + c + 4]) = o1;
}

extern "C" void kernel_launch(void* const* d_in, const int* in_sizes, int n_in,
                              void* d_out, int out_size, void* d_ws, size_t ws_size,
                              hipStream_t stream) {
    const float* x       = (const float*)d_in[0];
    const int*   ei      = (const int*)d_in[1];      // [2][E] int32
    const float* W       = (const float*)d_in[2];
    const float* att_src = (const float*)d_in[3];
    const float* att_dst = (const float*)d_in[4];
    const float* bias    = (const float*)d_in[5];
    float* out = (float*)d_out;

    char* ws = (char*)d_ws;
    size_t off = 0;
    auto alloc = [&](size_t bytes) -> void* {
        void* p = ws + off;
        off = (off + bytes + 255) & ~(size_t)255;
        return p;
    };
    unsigned short* xb   = (unsigned short*)alloc((size_t)M_PAD * D_DIM * 2);
    unsigned short* Wt   = (unsigned short*)alloc((size_t)D_DIM * D_DIM * 2);
    unsigned short* xpb  = (unsigned short*)alloc((size_t)M_PAD * D_DIM * 2);
    float* a_src    = (float*)alloc((size_t)N_NODES * 4 * 4);
    float* a_dst    = (float*)alloc((size_t)N_NODES * 4 * 4);
    int*   deg      = (int*)alloc((size_t)N_NODES * 4);
    int*   rowstart = (int*)alloc((size_t)(N_NODES + 1) * 4);
    int*   cursor   = (int*)alloc((size_t)N_NODES * 4);
    int*   blocksum = (int*)alloc((size_t)NBLK_SCAN * 4);
    int*   blockoff = (int*)alloc((size_t)128 * 4);
    int*   csr_src  = (int*)alloc((size_t)NE * 4);
    float* csr_ee   = (float*)alloc((size_t)NE * 4 * 4);

    hipMemsetAsync(deg, 0, (size_t)N_NODES * 4, stream);
    hipMemsetAsync(cursor, 0, (size_t)N_NODES * 4, stream);

    k_convert_x<<<M_PAD, 256, 0, stream>>>(x, xb);
    k_convert_wt<<<dim3(32, 32), dim3(32, 8), 0, stream>>>(W, Wt);
    k_gemm<<<dim3(M_PAD / 128, D_DIM / 128), 256, 0, stream>>>(xb, Wt, xpb);
    k_node_logits<<<N_NODES, 256, 0, stream>>>(xpb, att_src, att_dst, a_src, a_dst);
    k_deg<<<(NE + 255) / 256, 256, 0, stream>>>(ei, deg);
    k_scan1<<<NBLK_SCAN, 256, 0, stream>>>(deg, rowstart, blocksum);
    k_scan2<<<1, 128, 0, stream>>>(blocksum, blockoff);
    k_scan3<<<NBLK_SCAN, 256, 0, stream>>>(rowstart, blockoff);
    k_edge_exp_scatter<<<(NE + 255) / 256, 256, 0, stream>>>(
        ei, a_src, a_dst, rowstart, cursor, csr_src, csr_ee);
    k_node_aggregate<<<12500, 256, 0, stream>>>(
        csr_src, csr_ee, rowstart, xpb, bias, out);
}